// Round 16
// baseline (255.981 us; speedup 1.0000x reference)
//
#include <hip/hip_runtime.h>
#include <stdint.h>
#include <stddef.h>

typedef unsigned short u16;
typedef unsigned int   u32;

typedef __attribute__((ext_vector_type(8))) short bf16x8;
typedef __attribute__((ext_vector_type(4))) float f32x4;

__device__ __forceinline__ float b2f_lo(u32 v) { return __uint_as_float(v << 16); }
__device__ __forceinline__ float b2f_hi(u32 v) { return __uint_as_float(v & 0xFFFF0000u); }
__device__ __forceinline__ u16 f2b(float f){
  u32 x = __float_as_uint(f);
  return (u16)((x + 0x7FFFu + ((x >> 16) & 1u)) >> 16);
}
__device__ __forceinline__ int refl(int w){ return w < 0 ? -w : (w > 8191 ? 16382 - w : w); }
__device__ __forceinline__ void up8(const uint4 v, float* f){
  f[0] = b2f_lo(v.x); f[1] = b2f_hi(v.x); f[2] = b2f_lo(v.y); f[3] = b2f_hi(v.y);
  f[4] = b2f_lo(v.z); f[5] = b2f_hi(v.z); f[6] = b2f_lo(v.w); f[7] = b2f_hi(v.w);
}

// ---------------------------------------------------------------------------
// K0: build combined weight matrix Wall[896][256] (bf16) + fp32 bias ball[896].
// rows 0-255: w1/b1, 256-511: w2/b2, 512-767: w3/b3, 768-831: fc-folded, rest 0.
// ---------------------------------------------------------------------------
__global__ __launch_bounds__(256) void k_build(const float* __restrict__ w1, const float* __restrict__ b1,
                                               const float* __restrict__ w2, const float* __restrict__ b2,
                                               const float* __restrict__ w3, const float* __restrict__ b3,
                                               const float* __restrict__ fcw,
                                               u16* __restrict__ Wall, float* __restrict__ ball){
  const int r = blockIdx.x, c = threadIdx.x;
  float v = 0.f, bv = 0.f;
  if (r < 256){      v = w1[(r << 8) + c];          bv = b1[r]; }
  else if (r < 512){ v = w2[((r - 256) << 8) + c];  bv = b2[r - 256]; }
  else if (r < 768){ v = w3[((r - 512) << 8) + c];  bv = b3[r - 512]; }
  else if (r < 832){
    const int d = r - 768;
    float s = 0.f, sbias = 0.f;
#pragma unroll
    for (int h = 0; h < 4; ++h){
      const int ch = (h << 6) + d;
      const float f1 = fcw[h], f2 = fcw[4 + h], f3 = fcw[8 + h];
      s     += f1 * w1[(ch << 8) + c] + f2 * w2[(ch << 8) + c] + f3 * w3[(ch << 8) + c];
      sbias += f1 * b1[ch] + f2 * b2[ch] + f3 * b3[ch];
    }
    v = s; bv = sbias;
  }
  Wall[(r << 8) + c] = f2b(v);
  if (c == 0) ball[r] = bv;
}

// ---------------------------------------------------------------------------
// K1 (fused, 16-wave): per (b, 64-w stripe): stage x -> Bl, 26 quarter-tile
// GEMMs (M=32 each, A direct from L2-resident Wall -> NO inner barriers),
// epilogue routes q/k/v/f into swizzled LDS, 4-way-split attention + dep-conv.
//
// amdgpu_waves_per_eu(4,4): LDS (154KB) caps us at 1 block/CU = 4 waves/EU
// anyway; pin the register allocator to that occupancy -> VGPR budget 128.
// (R12/R13 post-mortem: default heuristic targets 8 waves/EU -> 64 VGPR ->
// spill -> 350MB scratch writes + L2 thrash making Wall reads miss (213MB
// HBM) -> 166us.  launch_bounds' 2nd arg is only a MIN floor - no-op here.)
//
// LDS map (bytes):
//   Bl  [80 r][256 k] bf16, chunk ^= (r&31)        40960   (r <-> w0-4+r)
//   Ql  [64 wl][256 ch] bf16, chunk ^= (wl&31)     32768
//   KVl [70 rr][512 ch] bf16, chunk ^= (rr&31)     71680   (rr <-> w0-3+rr)
//   Fl  [64 wl][64 ch]  bf16, chunk ^= (wl&7)       8192
//   wpL 64 f32                                       256
//   total 153856 B -> 1 block/CU, 16 waves = 4 waves/SIMD.
// Barriers: 2 total (post-staging, post-epilogue).
// grid 512 x 1024 threads.
// ---------------------------------------------------------------------------
__global__ __launch_bounds__(1024) __attribute__((amdgpu_waves_per_eu(4, 4))) void fused_acmix(
    const u16* __restrict__ Wall, const float* __restrict__ ball,
    const float* __restrict__ x, const float* __restrict__ wp,
    const float* __restrict__ depw, const float* __restrict__ depb,
    const float* __restrict__ r1p, const float* __restrict__ r2p,
    float* __restrict__ out)
{
  __shared__ __align__(16) u16 Bl [80 * 256];
  __shared__ __align__(16) u16 Ql [64 * 256];
  __shared__ __align__(16) u16 KVl[70 * 512];
  __shared__ __align__(16) u16 Fl [64 * 64];
  __shared__ float wpL[64];

  const int bid = blockIdx.x;
  const int w_id = ((bid & 7) << 6) + (bid >> 3);   // XCD-contiguous stripes
  const int b = w_id >> 7;                           // 0..3
  const int w0 = (w_id & 127) << 6;

  const int t = threadIdx.x;
  const int wave = t >> 6, lane = t & 63;
  const int quad = lane >> 4, l15 = lane & 15;

  if (t < 64) wpL[t] = wp[t];

  // ---- stage Bl: task idx = cc*80 + r (lanes walk consecutive r => coalesced w) ----
  {
    const float* xb = x + ((size_t)b << 21);         // b*256*8192
    for (int idx = t; idx < 2560; idx += 1024){
      const int cc = idx / 80;                       // 0..31 (8-channel chunk)
      const int r  = idx - cc * 80;                  // 0..79
      const int w  = refl(w0 - 4 + r);
      const float* px = xb + (((size_t)cc) << 16) + w;   // + cc*8*8192
      u32 pk[4];
#pragma unroll
      for (int jj = 0; jj < 4; ++jj){
        const float f0 = px[(size_t)(2 * jj)     << 13];
        const float f1 = px[(size_t)(2 * jj + 1) << 13];
        pk[jj] = (u32)f2b(f0) | ((u32)f2b(f1) << 16);
      }
      *(uint4*)((char*)Bl + r * 512 + ((cc ^ (r & 31)) << 4)) = make_uint4(pk[0], pk[1], pk[2], pk[3]);
    }
  }
  __syncthreads();

  // ---- GEMM: 26 quarter-tiles (qt = mt*4+mq; mt 0..5 full, mt 6 only mq<2).
  //      Wave w handles qt = w and w+16. A direct from global Wall (L2-hot). ----
  for (int qt = wave; qt < 26; qt += 16){
    const int mt = qt >> 2, mq = qt & 3;
    const int mbase = (mt << 7) + (mq << 5);
    f32x4 acc[2][5] = {};
#pragma unroll
    for (int kc = 0; kc < 4; ++kc){
#pragma unroll
      for (int ks = 0; ks < 2; ++ks){
        bf16x8 av[2], bv[5];
#pragma unroll
        for (int i = 0; i < 2; ++i){
          const int row = mbase + (i << 4) + l15;
          av[i] = *(const bf16x8*)(Wall + (row << 8) + (kc << 6) + (ks << 5) + (quad << 3));
        }
#pragma unroll
        for (int j = 0; j < 5; ++j){
          const int rowB = (j << 4) + l15;
          const int cb = ((kc << 3) + (ks << 2) + quad) ^ (rowB & 31);
          bv[j] = *(const bf16x8*)((const char*)Bl + rowB * 512 + (cb << 4));
        }
#pragma unroll
        for (int i = 0; i < 2; ++i)
#pragma unroll
          for (int j = 0; j < 5; ++j)
            acc[i][j] = __builtin_amdgcn_mfma_f32_16x16x32_bf16(av[i], bv[j], acc[i][j], 0, 0, 0);
      }
    }
    // epilogue: C[m=mbase+i*16+quad*4+reg][r=j*16+l15] -> route to LDS
#pragma unroll
    for (int i = 0; i < 2; ++i){
      const int mloc = (mq << 5) + (i << 4) + (quad << 2);     // 0..127 within mt
      const float4 bias = *(const float4*)(ball + (mt << 7) + mloc);
#pragma unroll
      for (int j = 0; j < 5; ++j){
        const int r = (j << 4) + l15;
        f32x4 c = acc[i][j];
        uint2 val;
        val.x = (u32)f2b(c.x + bias.x) | ((u32)f2b(c.y + bias.y) << 16);
        val.y = (u32)f2b(c.z + bias.z) | ((u32)f2b(c.w + bias.w) << 16);
        if (mt < 2){
          const int wl = r - 4;                                // q: center rows
          if ((unsigned)wl < 64u){
            const int chunk = ((mt << 7) + mloc) >> 3;
            *(uint2*)((char*)Ql + wl * 512 + ((chunk ^ (wl & 31)) << 4) + ((quad & 1) << 3)) = val;
          }
        } else if (mt < 6){
          const int rr = r - 1;                                // k/v: 70 halo rows
          if ((unsigned)rr < 70u){
            const int chunk = (((mt - 2) << 7) + mloc) >> 3;   // k: 0..31, v: 32..63
            *(uint2*)((char*)KVl + rr * 1024 + ((chunk ^ (rr & 31)) << 4) + ((quad & 1) << 3)) = val;
          }
        } else {
          const int wl = r - 4;                                // f: mq<2 => mloc<64
          if ((unsigned)wl < 64u){
            const int chunk = mloc >> 3;                       // 0..7
            *(uint2*)((char*)Fl + wl * 128 + ((chunk ^ (wl & 7)) << 4) + ((quad & 1) << 3)) = val;
          }
        }
      }
    }
  }
  __syncthreads();

  // ---- attention: thread = (es = t&3, h, wl); es handles e in {2es, 2es+1} ----
  const int es = t & 3;
  const int q_ = t >> 2;                 // 0..255
  const int h = q_ >> 6, wl = q_ & 63;
  const int w = w0 + wl;

  float att[7] = {0.f,0.f,0.f,0.f,0.f,0.f,0.f};
  float qd = 0.f;
#pragma unroll
  for (int ee = 0; ee < 2; ++ee){
    const int e = (es << 1) + ee;
    const int cq = (h << 3) + e;
    const uint4 q4 = *(const uint4*)((const char*)Ql + wl * 512 + ((cq ^ (wl & 31)) << 4));
    float qf[8]; up8(q4, qf);
#pragma unroll
    for (int d = 0; d < 8; ++d) qd += qf[d] * wpL[(e << 3) + d];
#pragma unroll
    for (int kk = 0; kk < 7; ++kk){
      const int rr = wl + kk;
      const uint4 k4 = *(const uint4*)((const char*)KVl + rr * 1024 + ((cq ^ (rr & 31)) << 4));
      float kf[8]; up8(k4, kf);
      att[kk] += qf[0]*kf[0] + qf[1]*kf[1] + qf[2]*kf[2] + qf[3]*kf[3]
               + qf[4]*kf[4] + qf[5]*kf[5] + qf[6]*kf[6] + qf[7]*kf[7];
    }
  }
  // reduce partials across the 4 es lanes (adjacent lanes; no barrier needed)
#pragma unroll
  for (int kk = 0; kk < 7; ++kk){
    att[kk] += __shfl_xor(att[kk], 1);
    att[kk] += __shfl_xor(att[kk], 2);
  }
  qd += __shfl_xor(qd, 1);
  qd += __shfl_xor(qd, 2);

  // positional term + scale + softmax (redundant x4, cheap)
  const float locw = -1.f + (2.f / 8191.f) * (float)w;
  float mx = -1e30f;
#pragma unroll
  for (int kk = 0; kk < 7; ++kk){
    const int wr = refl(w + kk - 3);
    const float lr = -1.f + (2.f / 8191.f) * (float)wr;
    att[kk] = 0.125f * (att[kk] + (locw - lr) * qd);
    mx = fmaxf(mx, att[kk]);
  }
  float p[7]; float ssum = 0.f;
#pragma unroll
  for (int kk = 0; kk < 7; ++kk){ p[kk] = __expf(att[kk] - mx); ssum += p[kk]; }
  const float inv = 1.f / ssum;
#pragma unroll
  for (int kk = 0; kk < 7; ++kk) p[kk] *= inv;

  // f values for this thread's dl range (f channels h*16 + es*4 .. +3)
  float fq[4];
  {
    const int cf = (h << 1) + (es >> 1);
    const uint2 fb = *(const uint2*)((const char*)Fl + wl * 128 + ((cf ^ (wl & 7)) << 4) + ((es & 1) << 3));
    fq[0] = b2f_lo(fb.x); fq[1] = b2f_hi(fb.x);
    fq[2] = b2f_lo(fb.y); fq[3] = b2f_hi(fb.y);
  }
  const float r1 = r1p[0];
  const float r2 = r2p[0];

  // PV + dep-conv + combine + store (16 channels per thread)
#pragma unroll
  for (int ee = 0; ee < 2; ++ee){
    const int e = (es << 1) + ee;
    float o8[8] = {0.f,0.f,0.f,0.f,0.f,0.f,0.f,0.f};
#pragma unroll
    for (int kk = 0; kk < 7; ++kk){
      const int rr = wl + kk;
      const uint4 v4 = *(const uint4*)((const char*)KVl + rr * 1024 + (((32 + (h << 3) + e) ^ (rr & 31)) << 4));
      float vf[8]; up8(v4, vf);
      const float pk = p[kk];
      o8[0] += pk * vf[0]; o8[1] += pk * vf[1]; o8[2] += pk * vf[2]; o8[3] += pk * vf[3];
      o8[4] += pk * vf[4]; o8[5] += pk * vf[5]; o8[6] += pk * vf[6]; o8[7] += pk * vf[7];
    }
#pragma unroll
    for (int s = 0; s < 8; ++s){
      const int dl = (e << 3) + s;
      const float oc = depw[(h << 6) + dl] * fq[(ee << 1) + (s >> 2)] + depb[(h << 6) + dl];
      out[(((size_t)((b << 8) + (h << 6) + dl)) << 13) + w] = r1 * o8[s] + r2 * oc;
    }
  }
}

// ---------------------------------------------------------------------------
// launch
// ---------------------------------------------------------------------------
extern "C" void kernel_launch(void* const* d_in, const int* in_sizes, int n_in,
                              void* d_out, int out_size, void* d_ws, size_t ws_size,
                              hipStream_t stream){
  (void)in_sizes; (void)n_in; (void)out_size; (void)ws_size;
  const float* x    = (const float*)d_in[0];
  const float* w1   = (const float*)d_in[1];
  const float* b1   = (const float*)d_in[2];
  const float* w2   = (const float*)d_in[3];
  const float* b2   = (const float*)d_in[4];
  const float* w3   = (const float*)d_in[5];
  const float* b3   = (const float*)d_in[6];
  const float* wp   = (const float*)d_in[7];
  // d_in[8] = bp : cancels analytically (pe - unfolded pe), unused
  const float* fcw  = (const float*)d_in[9];
  const float* depw = (const float*)d_in[10];
  const float* depb = (const float*)d_in[11];
  const float* r1p  = (const float*)d_in[12];
  const float* r2p  = (const float*)d_in[13];
  float* out = (float*)d_out;

  char* ws = (char*)d_ws;
  u16*   Wall = (u16*)(ws);                 // 896*256*2 = 458,752 B
  float* ball = (float*)(ws + 458752);      // 896*4     =   3,584 B

  k_build<<<dim3(896, 1, 1), 256, 0, stream>>>(w1, b1, w2, b2, w3, b3, fcw, Wall, ball);
  fused_acmix<<<dim3(512, 1, 1), 1024, 0, stream>>>(Wall, ball, x, wp, depw, depb, r1p, r2p, out);
}

// Round 17
// 255.948 us; speedup vs baseline: 1.0001x; 1.0001x over previous
//
#include <hip/hip_runtime.h>
#include <stdint.h>
#include <stddef.h>

typedef unsigned short u16;
typedef unsigned int   u32;

typedef __attribute__((ext_vector_type(8))) short bf16x8;
typedef __attribute__((ext_vector_type(4))) float f32x4;

__device__ __forceinline__ float b2f_lo(u32 v) { return __uint_as_float(v << 16); }
__device__ __forceinline__ float b2f_hi(u32 v) { return __uint_as_float(v & 0xFFFF0000u); }
__device__ __forceinline__ u16 f2b(float f){
  u32 x = __float_as_uint(f);
  return (u16)((x + 0x7FFFu + ((x >> 16) & 1u)) >> 16);
}
__device__ __forceinline__ int refl(int w){ return w < 0 ? -w : (w > 8191 ? 16382 - w : w); }
__device__ __forceinline__ void up8(const uint4 v, float* f){
  f[0] = b2f_lo(v.x); f[1] = b2f_hi(v.x); f[2] = b2f_lo(v.y); f[3] = b2f_hi(v.y);
  f[4] = b2f_lo(v.z); f[5] = b2f_hi(v.z); f[6] = b2f_lo(v.w); f[7] = b2f_hi(v.w);
}

// ---------------------------------------------------------------------------
// K0: build combined weight matrix Wall[896][256] (bf16) + fp32 bias ball[896].
// rows 0-255: w1/b1, 256-511: w2/b2, 512-767: w3/b3, 768-831: fc-folded, rest 0.
// ---------------------------------------------------------------------------
__global__ __launch_bounds__(256) void k_build(const float* __restrict__ w1, const float* __restrict__ b1,
                                               const float* __restrict__ w2, const float* __restrict__ b2,
                                               const float* __restrict__ w3, const float* __restrict__ b3,
                                               const float* __restrict__ fcw,
                                               u16* __restrict__ Wall, float* __restrict__ ball){
  const int r = blockIdx.x, c = threadIdx.x;
  float v = 0.f, bv = 0.f;
  if (r < 256){      v = w1[(r << 8) + c];          bv = b1[r]; }
  else if (r < 512){ v = w2[((r - 256) << 8) + c];  bv = b2[r - 256]; }
  else if (r < 768){ v = w3[((r - 512) << 8) + c];  bv = b3[r - 512]; }
  else if (r < 832){
    const int d = r - 768;
    float s = 0.f, sbias = 0.f;
#pragma unroll
    for (int h = 0; h < 4; ++h){
      const int ch = (h << 6) + d;
      const float f1 = fcw[h], f2 = fcw[4 + h], f3 = fcw[8 + h];
      s     += f1 * w1[(ch << 8) + c] + f2 * w2[(ch << 8) + c] + f3 * w3[(ch << 8) + c];
      sbias += f1 * b1[ch] + f2 * b2[ch] + f3 * b3[ch];
    }
    v = s; bv = sbias;
  }
  Wall[(r << 8) + c] = f2b(v);
  if (c == 0) ball[r] = bv;
}

// ---------------------------------------------------------------------------
// K1 (fused, 16-wave): per (b, 64-w stripe): stage x -> Bl, GEMMs with A
// direct from L2-resident Wall (no inner barriers), epilogue routes q/k/v/f
// into swizzled LDS, 4-way-split attention + dep-conv.
//
// R12-R16 post-mortem: allocator pinned arch-VGPRs at 64 under THREE
// occupancy attributes (bit-identical binaries); GEMM live set ~90 -> spill
// -> 310MB scratch writes + 210MB restores/L2-thrash -> 166us.  Fix is
// STRUCTURAL: each qt is processed as two independent 16-row half-passes
// (ih=0,1), each with acc[5] (20 regs) + single av + per-j bv + immediate
// epilogue.  Worst-case live ~56 <= 64 -> no spill at any allocator target.
// Cost: Bl read twice per qt (LDS has ~5x headroom).
//
// LDS map (bytes):
//   Bl  [80 r][256 k] bf16, chunk ^= (r&31)        40960   (r <-> w0-4+r)
//   Ql  [64 wl][256 ch] bf16, chunk ^= (wl&31)     32768
//   KVl [70 rr][512 ch] bf16, chunk ^= (rr&31)     71680   (rr <-> w0-3+rr)
//   Fl  [64 wl][64 ch]  bf16, chunk ^= (wl&7)       8192
//   wpL 64 f32                                       256
//   total 153856 B -> 1 block/CU, 16 waves = 4 waves/SIMD.
// Barriers: 2 total (post-staging, post-epilogue).
// grid 512 x 1024 threads.
// ---------------------------------------------------------------------------
__global__ __launch_bounds__(1024) __attribute__((amdgpu_waves_per_eu(4, 4))) void fused_acmix(
    const u16* __restrict__ Wall, const float* __restrict__ ball,
    const float* __restrict__ x, const float* __restrict__ wp,
    const float* __restrict__ depw, const float* __restrict__ depb,
    const float* __restrict__ r1p, const float* __restrict__ r2p,
    float* __restrict__ out)
{
  __shared__ __align__(16) u16 Bl [80 * 256];
  __shared__ __align__(16) u16 Ql [64 * 256];
  __shared__ __align__(16) u16 KVl[70 * 512];
  __shared__ __align__(16) u16 Fl [64 * 64];
  __shared__ float wpL[64];

  const int bid = blockIdx.x;
  const int w_id = ((bid & 7) << 6) + (bid >> 3);   // XCD-contiguous stripes
  const int b = w_id >> 7;                           // 0..3
  const int w0 = (w_id & 127) << 6;

  const int t = threadIdx.x;
  const int wave = t >> 6, lane = t & 63;
  const int quad = lane >> 4, l15 = lane & 15;

  if (t < 64) wpL[t] = wp[t];

  // ---- stage Bl: task idx = cc*80 + r (lanes walk consecutive r => coalesced w) ----
  {
    const float* xb = x + ((size_t)b << 21);         // b*256*8192
    for (int idx = t; idx < 2560; idx += 1024){
      const int cc = idx / 80;                       // 0..31 (8-channel chunk)
      const int r  = idx - cc * 80;                  // 0..79
      const int w  = refl(w0 - 4 + r);
      const float* px = xb + (((size_t)cc) << 16) + w;   // + cc*8*8192
      u32 pk[4];
#pragma unroll
      for (int jj = 0; jj < 4; ++jj){
        const float f0 = px[(size_t)(2 * jj)     << 13];
        const float f1 = px[(size_t)(2 * jj + 1) << 13];
        pk[jj] = (u32)f2b(f0) | ((u32)f2b(f1) << 16);
      }
      *(uint4*)((char*)Bl + r * 512 + ((cc ^ (r & 31)) << 4)) = make_uint4(pk[0], pk[1], pk[2], pk[3]);
    }
  }
  __syncthreads();

  // ---- GEMM: 26 quarter-tiles (qt = mt*4+mq; mt 0..5 full, mt 6 only mq<2).
  //      Wave w handles qt = w and w+16.  Each qt = two 16-row half-passes. ----
  for (int qt = wave; qt < 26; qt += 16){
    const int mt = qt >> 2, mq = qt & 3;
    const int mbase = (mt << 7) + (mq << 5);
#pragma unroll
    for (int ih = 0; ih < 2; ++ih){
      const int rowA = mbase + (ih << 4) + l15;
      f32x4 acc[5] = {};
#pragma unroll
      for (int kc = 0; kc < 4; ++kc){
#pragma unroll
        for (int ks = 0; ks < 2; ++ks){
          const bf16x8 av = *(const bf16x8*)(Wall + (rowA << 8) + (kc << 6) + (ks << 5) + (quad << 3));
#pragma unroll
          for (int j = 0; j < 5; ++j){
            const int rowB = (j << 4) + l15;
            const int cb = ((kc << 3) + (ks << 2) + quad) ^ (rowB & 31);
            const bf16x8 bv = *(const bf16x8*)((const char*)Bl + rowB * 512 + (cb << 4));
            acc[j] = __builtin_amdgcn_mfma_f32_16x16x32_bf16(av, bv, acc[j], 0, 0, 0);
          }
        }
      }
      // epilogue for these 16 rows: C[m=mbase+ih*16+quad*4+reg][r=j*16+l15]
      const int mloc = (mq << 5) + (ih << 4) + (quad << 2);    // 0..127 within mt
      const float4 bias = *(const float4*)(ball + (mt << 7) + mloc);
#pragma unroll
      for (int j = 0; j < 5; ++j){
        const int r = (j << 4) + l15;
        f32x4 c = acc[j];
        uint2 val;
        val.x = (u32)f2b(c.x + bias.x) | ((u32)f2b(c.y + bias.y) << 16);
        val.y = (u32)f2b(c.z + bias.z) | ((u32)f2b(c.w + bias.w) << 16);
        if (mt < 2){
          const int wl = r - 4;                                // q: center rows
          if ((unsigned)wl < 64u){
            const int chunk = ((mt << 7) + mloc) >> 3;
            *(uint2*)((char*)Ql + wl * 512 + ((chunk ^ (wl & 31)) << 4) + ((quad & 1) << 3)) = val;
          }
        } else if (mt < 6){
          const int rr = r - 1;                                // k/v: 70 halo rows
          if ((unsigned)rr < 70u){
            const int chunk = (((mt - 2) << 7) + mloc) >> 3;   // k: 0..31, v: 32..63
            *(uint2*)((char*)KVl + rr * 1024 + ((chunk ^ (rr & 31)) << 4) + ((quad & 1) << 3)) = val;
          }
        } else {
          const int wl = r - 4;                                // f: mq<2 => mloc<64
          if ((unsigned)wl < 64u){
            const int chunk = mloc >> 3;                       // 0..7
            *(uint2*)((char*)Fl + wl * 128 + ((chunk ^ (wl & 7)) << 4) + ((quad & 1) << 3)) = val;
          }
        }
      }
    }
  }
  __syncthreads();

  // ---- attention: thread = (es = t&3, h, wl); es handles e in {2es, 2es+1} ----
  const int es = t & 3;
  const int q_ = t >> 2;                 // 0..255
  const int h = q_ >> 6, wl = q_ & 63;
  const int w = w0 + wl;

  float att[7] = {0.f,0.f,0.f,0.f,0.f,0.f,0.f};
  float qd = 0.f;
#pragma unroll
  for (int ee = 0; ee < 2; ++ee){
    const int e = (es << 1) + ee;
    const int cq = (h << 3) + e;
    const uint4 q4 = *(const uint4*)((const char*)Ql + wl * 512 + ((cq ^ (wl & 31)) << 4));
    float qf[8]; up8(q4, qf);
#pragma unroll
    for (int d = 0; d < 8; ++d) qd += qf[d] * wpL[(e << 3) + d];
#pragma unroll
    for (int kk = 0; kk < 7; ++kk){
      const int rr = wl + kk;
      const uint4 k4 = *(const uint4*)((const char*)KVl + rr * 1024 + ((cq ^ (rr & 31)) << 4));
      float kf[8]; up8(k4, kf);
      att[kk] += qf[0]*kf[0] + qf[1]*kf[1] + qf[2]*kf[2] + qf[3]*kf[3]
               + qf[4]*kf[4] + qf[5]*kf[5] + qf[6]*kf[6] + qf[7]*kf[7];
    }
  }
  // reduce partials across the 4 es lanes (adjacent lanes; no barrier needed)
#pragma unroll
  for (int kk = 0; kk < 7; ++kk){
    att[kk] += __shfl_xor(att[kk], 1);
    att[kk] += __shfl_xor(att[kk], 2);
  }
  qd += __shfl_xor(qd, 1);
  qd += __shfl_xor(qd, 2);

  // positional term + scale + softmax (redundant x4, cheap)
  const float locw = -1.f + (2.f / 8191.f) * (float)w;
  float mx = -1e30f;
#pragma unroll
  for (int kk = 0; kk < 7; ++kk){
    const int wr = refl(w + kk - 3);
    const float lr = -1.f + (2.f / 8191.f) * (float)wr;
    att[kk] = 0.125f * (att[kk] + (locw - lr) * qd);
    mx = fmaxf(mx, att[kk]);
  }
  float p[7]; float ssum = 0.f;
#pragma unroll
  for (int kk = 0; kk < 7; ++kk){ p[kk] = __expf(att[kk] - mx); ssum += p[kk]; }
  const float inv = 1.f / ssum;
#pragma unroll
  for (int kk = 0; kk < 7; ++kk) p[kk] *= inv;

  // f values for this thread's dl range (f channels h*16 + es*4 .. +3)
  float fq[4];
  {
    const int cf = (h << 1) + (es >> 1);
    const uint2 fb = *(const uint2*)((const char*)Fl + wl * 128 + ((cf ^ (wl & 7)) << 4) + ((es & 1) << 3));
    fq[0] = b2f_lo(fb.x); fq[1] = b2f_hi(fb.x);
    fq[2] = b2f_lo(fb.y); fq[3] = b2f_hi(fb.y);
  }
  const float r1 = r1p[0];
  const float r2 = r2p[0];

  // PV + dep-conv + combine + store (16 channels per thread)
#pragma unroll
  for (int ee = 0; ee < 2; ++ee){
    const int e = (es << 1) + ee;
    float o8[8] = {0.f,0.f,0.f,0.f,0.f,0.f,0.f,0.f};
#pragma unroll
    for (int kk = 0; kk < 7; ++kk){
      const int rr = wl + kk;
      const uint4 v4 = *(const uint4*)((const char*)KVl + rr * 1024 + (((32 + (h << 3) + e) ^ (rr & 31)) << 4));
      float vf[8]; up8(v4, vf);
      const float pk = p[kk];
      o8[0] += pk * vf[0]; o8[1] += pk * vf[1]; o8[2] += pk * vf[2]; o8[3] += pk * vf[3];
      o8[4] += pk * vf[4]; o8[5] += pk * vf[5]; o8[6] += pk * vf[6]; o8[7] += pk * vf[7];
    }
#pragma unroll
    for (int s = 0; s < 8; ++s){
      const int dl = (e << 3) + s;
      const float oc = depw[(h << 6) + dl] * fq[(ee << 1) + (s >> 2)] + depb[(h << 6) + dl];
      out[(((size_t)((b << 8) + (h << 6) + dl)) << 13) + w] = r1 * o8[s] + r2 * oc;
    }
  }
}

// ---------------------------------------------------------------------------
// launch
// ---------------------------------------------------------------------------
extern "C" void kernel_launch(void* const* d_in, const int* in_sizes, int n_in,
                              void* d_out, int out_size, void* d_ws, size_t ws_size,
                              hipStream_t stream){
  (void)in_sizes; (void)n_in; (void)out_size; (void)ws_size;
  const float* x    = (const float*)d_in[0];
  const float* w1   = (const float*)d_in[1];
  const float* b1   = (const float*)d_in[2];
  const float* w2   = (const float*)d_in[3];
  const float* b2   = (const float*)d_in[4];
  const float* w3   = (const float*)d_in[5];
  const float* b3   = (const float*)d_in[6];
  const float* wp   = (const float*)d_in[7];
  // d_in[8] = bp : cancels analytically (pe - unfolded pe), unused
  const float* fcw  = (const float*)d_in[9];
  const float* depw = (const float*)d_in[10];
  const float* depb = (const float*)d_in[11];
  const float* r1p  = (const float*)d_in[12];
  const float* r2p  = (const float*)d_in[13];
  float* out = (float*)d_out;

  char* ws = (char*)d_ws;
  u16*   Wall = (u16*)(ws);                 // 896*256*2 = 458,752 B
  float* ball = (float*)(ws + 458752);      // 896*4     =   3,584 B

  k_build<<<dim3(896, 1, 1), 256, 0, stream>>>(w1, b1, w2, b2, w3, b3, fcw, Wall, ball);
  fused_acmix<<<dim3(512, 1, 1), 1024, 0, stream>>>(Wall, ball, x, wp, depw, depb, r1p, r2p, out);
}

// Round 21
// 205.080 us; speedup vs baseline: 1.2482x; 1.2480x over previous
//
#include <hip/hip_runtime.h>
#include <stdint.h>
#include <stddef.h>

typedef unsigned short u16;
typedef unsigned int   u32;

typedef __attribute__((ext_vector_type(8))) short bf16x8;
typedef __attribute__((ext_vector_type(4))) float f32x4;

__device__ __forceinline__ float b2f_lo(u32 v) { return __uint_as_float(v << 16); }
__device__ __forceinline__ float b2f_hi(u32 v) { return __uint_as_float(v & 0xFFFF0000u); }
__device__ __forceinline__ u16 f2b(float f){
  u32 x = __float_as_uint(f);
  return (u16)((x + 0x7FFFu + ((x >> 16) & 1u)) >> 16);
}
__device__ __forceinline__ int refl(int w){ return w < 0 ? -w : (w > 8191 ? 16382 - w : w); }
__device__ __forceinline__ void up8(const uint4 v, float* f){
  f[0] = b2f_lo(v.x); f[1] = b2f_hi(v.x); f[2] = b2f_lo(v.y); f[3] = b2f_hi(v.y);
  f[4] = b2f_lo(v.z); f[5] = b2f_hi(v.z); f[6] = b2f_lo(v.w); f[7] = b2f_hi(v.w);
}

// ---------------------------------------------------------------------------
// K0: build combined weight matrix Wall[896][256] (bf16) + fp32 bias ball[896].
// rows 0-255: w1/b1, 256-511: w2/b2, 512-767: w3/b3, 768-831: fc-folded, rest 0.
// ---------------------------------------------------------------------------
__global__ __launch_bounds__(256) void k_build(const float* __restrict__ w1, const float* __restrict__ b1,
                                               const float* __restrict__ w2, const float* __restrict__ b2,
                                               const float* __restrict__ w3, const float* __restrict__ b3,
                                               const float* __restrict__ fcw,
                                               u16* __restrict__ Wall, float* __restrict__ ball){
  const int r = blockIdx.x, c = threadIdx.x;
  float v = 0.f, bv = 0.f;
  if (r < 256){      v = w1[(r << 8) + c];          bv = b1[r]; }
  else if (r < 512){ v = w2[((r - 256) << 8) + c];  bv = b2[r - 256]; }
  else if (r < 768){ v = w3[((r - 512) << 8) + c];  bv = b3[r - 512]; }
  else if (r < 832){
    const int d = r - 768;
    float s = 0.f, sbias = 0.f;
#pragma unroll
    for (int h = 0; h < 4; ++h){
      const int ch = (h << 6) + d;
      const float f1 = fcw[h], f2 = fcw[4 + h], f3 = fcw[8 + h];
      s     += f1 * w1[(ch << 8) + c] + f2 * w2[(ch << 8) + c] + f3 * w3[(ch << 8) + c];
      sbias += f1 * b1[ch] + f2 * b2[ch] + f3 * b3[ch];
    }
    v = s; bv = sbias;
  }
  Wall[(r << 8) + c] = f2b(v);
  if (c == 0) ball[r] = bv;
}

// ---------------------------------------------------------------------------
// K1 (fused, 8-wave GEMM + R5-verbatim attention).
// R18 post-mortem: first-run PASS then post-timing divergence (absmax 0.845)
// with the new es-split attention.  Static audit found no race; to ISOLATE,
// this round keeps the 8-wave GEMM (byte-equivalent barrier scheme to R5's
// proven 4-wave version) and reverts attention to R5's exact per-thread code
// on threads 0..255 (waves 4..7 idle after the final barrier - uniform exit).
// If this fails the same way, the 8-wave GEMM is implicated (3-barrier probe
// next); if it passes, R18's bug was the es-split.
//
// LDS map (bytes):
//   Bl  [80 r][256 k] bf16, chunk ^= (r&31)        40960   (r <-> w0-4+r)
//   As  [128 m][64 k] bf16, chunk ^= (row&7)       16384   (aliased by f tile)
//   Ql  [64 wl][256 ch] bf16, chunk ^= (wl&31)     32768
//   KVl [70 rr][512 ch] bf16, chunk ^= (rr&31)     71680   (rr <-> w0-3+rr)
//   wpL 64 f32                                       256
//   total 162048 B -> 1 block/CU, 8 waves = 2 waves/SIMD.
// grid 512 x 512 threads.
// ---------------------------------------------------------------------------
__global__ __launch_bounds__(512, 1) void fused_acmix(
    const u16* __restrict__ Wall, const float* __restrict__ ball,
    const float* __restrict__ x, const float* __restrict__ wp,
    const float* __restrict__ depw, const float* __restrict__ depb,
    const float* __restrict__ r1p, const float* __restrict__ r2p,
    float* __restrict__ out)
{
  __shared__ __align__(16) u16 Bl [80 * 256];
  __shared__ __align__(16) u16 As [128 * 64];
  __shared__ __align__(16) u16 Ql [64 * 256];
  __shared__ __align__(16) u16 KVl[70 * 512];
  __shared__ float wpL[64];
  u16* Fl = As;   // f tile aliases As after the last GEMM (guarded by barrier)

  const int bid = blockIdx.x;
  const int w_id = ((bid & 7) << 6) + (bid >> 3);   // XCD-contiguous stripes
  const int b = w_id >> 7;                           // 0..3
  const int w0 = (w_id & 127) << 6;

  const int t = threadIdx.x;
  const int wv = t >> 6, lane = t & 63;
  const int quad = lane >> 4, l15 = lane & 15;

  if (t < 64) wpL[t] = wp[t];

  // ---- stage Bl: task idx = cc*80 + r (lanes walk consecutive r => coalesced w) ----
  {
    const float* xb = x + ((size_t)b << 21);         // b*256*8192
    for (int idx = t; idx < 2560; idx += 512){
      const int cc = idx / 80;                       // 0..31 (8-channel chunk)
      const int r  = idx - cc * 80;                  // 0..79
      const int w  = refl(w0 - 4 + r);
      const float* px = xb + (((size_t)cc) << 16) + w;   // + cc*8*8192
      u32 pk[4];
#pragma unroll
      for (int jj = 0; jj < 4; ++jj){
        const float f0 = px[(size_t)(2 * jj)     << 13];
        const float f1 = px[(size_t)(2 * jj + 1) << 13];
        pk[jj] = (u32)f2b(f0) | ((u32)f2b(f1) << 16);
      }
      *(uint4*)((char*)Bl + r * 512 + ((cc ^ (r & 31)) << 4)) = make_uint4(pk[0], pk[1], pk[2], pk[3]);
    }
  }

  // ---- GEMM phase: 7 mt tiles (q q k k v v f), K=256 in 4 chunks of 64.
  //      8 waves; wave wv owns the 16-row strip mloc = wv*16..wv*16+15. ----
  uint4 ra[2];
  auto loadA = [&](int mt_, int kc_){
#pragma unroll
    for (int k4 = 0; k4 < 2; ++k4){
      const int task = t + (k4 << 9);               // 0..1023
      const int row = task >> 3, u = task & 7;
      ra[k4] = *(const uint4*)(Wall + (((mt_ << 7) + row) << 8) + (kc_ << 6) + (u << 3));
    }
  };
  loadA(0, 0);

#pragma unroll
  for (int mt = 0; mt < 7; ++mt){
    f32x4 acc[5] = {};
#pragma unroll
    for (int kc = 0; kc < 4; ++kc){
      __syncthreads();                              // As safe to overwrite (also fences Bl on iter 0)
#pragma unroll
      for (int k4 = 0; k4 < 2; ++k4){
        const int task = t + (k4 << 9);
        const int row = task >> 3, u = (task & 7) ^ (row & 7);
        *(uint4*)((char*)As + row * 128 + (u << 4)) = ra[k4];
      }
      __syncthreads();
      {
        const int idx = (mt << 2) + kc;
        if (idx < 27) loadA((idx + 1) >> 2, (idx + 1) & 3);  // prefetch next A-tile under MFMA
      }
#pragma unroll
      for (int ks = 0; ks < 2; ++ks){
        const int rowA = (wv << 4) + l15;
        const int ca = ((ks << 2) + quad) ^ (rowA & 7);
        const bf16x8 av = *(const bf16x8*)((const char*)As + rowA * 128 + (ca << 4));
#pragma unroll
        for (int j = 0; j < 5; ++j){
          const int rowB = (j << 4) + l15;
          const int cb = ((kc << 3) + (ks << 2) + quad) ^ (rowB & 31);
          const bf16x8 bv = *(const bf16x8*)((const char*)Bl + rowB * 512 + (cb << 4));
          acc[j] = __builtin_amdgcn_mfma_f32_16x16x32_bf16(av, bv, acc[j], 0, 0, 0);
        }
      }
    }

    // epilogue: C[m = wv*16+quad*4+reg][r = j*16+l15] -> route to LDS
    if (mt == 6) __syncthreads();                   // all As reads done before f-alias writes
    const int mloc = (wv << 4) + (quad << 2);       // 0..124 within mt
    const float4 bias = *(const float4*)(ball + (mt << 7) + mloc);
#pragma unroll
    for (int j = 0; j < 5; ++j){
      const int r = (j << 4) + l15;
      f32x4 c = acc[j];
      uint2 val;
      val.x = (u32)f2b(c.x + bias.x) | ((u32)f2b(c.y + bias.y) << 16);
      val.y = (u32)f2b(c.z + bias.z) | ((u32)f2b(c.w + bias.w) << 16);
      if (mt < 2){
        const int wl = r - 4;                       // q: center rows only
        if ((unsigned)wl < 64u){
          const int chunk = ((mt << 7) + mloc) >> 3;
          *(uint2*)((char*)Ql + wl * 512 + ((chunk ^ (wl & 31)) << 4) + ((quad & 1) << 3)) = val;
        }
      } else if (mt < 6){
        const int rr = r - 1;                       // k/v: 70 halo rows
        if ((unsigned)rr < 70u){
          const int chunk = (((mt - 2) << 7) + mloc) >> 3;   // k: 0..31, v: 32..63
          *(uint2*)((char*)KVl + rr * 1024 + ((chunk ^ (rr & 31)) << 4) + ((quad & 1) << 3)) = val;
        }
      } else {
        const int wl = r - 4;                       // f: center rows, first 64 m only
        if ((unsigned)wl < 64u && mloc < 64){
          const int chunk = mloc >> 3;              // 0..7
          *(uint2*)((char*)Fl + wl * 128 + ((chunk ^ (wl & 7)) << 4) + ((quad & 1) << 3)) = val;
        }
      }
    }
  }
  __syncthreads();

  // ---- attention phase: R5-verbatim, threads 0..255 (one per (h,wl));
  //      waves 4..7 exit (uniform per wave; no barriers below). ----
  if (t < 256){
    const int h = t >> 6, wl = t & 63;
    const int w = w0 + wl;

    float att[7] = {0.f,0.f,0.f,0.f,0.f,0.f,0.f};
    float qd = 0.f;
#pragma unroll
    for (int e = 0; e < 8; ++e){
      const int cq = (h << 3) + e;
      const uint4 q4 = *(const uint4*)((const char*)Ql + wl * 512 + ((cq ^ (wl & 31)) << 4));
      float qf[8]; up8(q4, qf);
#pragma unroll
      for (int d = 0; d < 8; ++d) qd += qf[d] * wpL[(e << 3) + d];
#pragma unroll
      for (int kk = 0; kk < 7; ++kk){
        const int rr = wl + kk;
        const uint4 k4 = *(const uint4*)((const char*)KVl + rr * 1024 + ((cq ^ (rr & 31)) << 4));
        float kf[8]; up8(k4, kf);
        att[kk] += qf[0]*kf[0] + qf[1]*kf[1] + qf[2]*kf[2] + qf[3]*kf[3]
                 + qf[4]*kf[4] + qf[5]*kf[5] + qf[6]*kf[6] + qf[7]*kf[7];
      }
    }

    // positional term + scale + softmax
    const float locw = -1.f + (2.f / 8191.f) * (float)w;
    float mx = -1e30f;
#pragma unroll
    for (int kk = 0; kk < 7; ++kk){
      const int wr = refl(w + kk - 3);
      const float lr = -1.f + (2.f / 8191.f) * (float)wr;
      att[kk] = 0.125f * (att[kk] + (locw - lr) * qd);
      mx = fmaxf(mx, att[kk]);
    }
    float p[7]; float ssum = 0.f;
#pragma unroll
    for (int kk = 0; kk < 7; ++kk){ p[kk] = __expf(att[kk] - mx); ssum += p[kk]; }
    const float inv = 1.f / ssum;
#pragma unroll
    for (int kk = 0; kk < 7; ++kk) p[kk] *= inv;

    // f values for dep-conv (16 per head)
    float fvv[16];
    {
      const int c0 = h << 1;
      const uint4 f0 = *(const uint4*)((const char*)Fl + wl * 128 + ((c0 ^ (wl & 7)) << 4));
      const uint4 f1 = *(const uint4*)((const char*)Fl + wl * 128 + (((c0 + 1) ^ (wl & 7)) << 4));
      up8(f0, fvv); up8(f1, fvv + 8);
    }

    const float r1 = r1p[0];
    const float r2 = r2p[0];

    // PV + dep-conv + combine + store
#pragma unroll
    for (int e = 0; e < 8; ++e){
      float o8[8] = {0.f,0.f,0.f,0.f,0.f,0.f,0.f,0.f};
#pragma unroll
      for (int kk = 0; kk < 7; ++kk){
        const int rr = wl + kk;
        const uint4 v4 = *(const uint4*)((const char*)KVl + rr * 1024 + (((32 + (h << 3) + e) ^ (rr & 31)) << 4));
        float vf[8]; up8(v4, vf);
        const float pk = p[kk];
        o8[0] += pk * vf[0]; o8[1] += pk * vf[1]; o8[2] += pk * vf[2]; o8[3] += pk * vf[3];
        o8[4] += pk * vf[4]; o8[5] += pk * vf[5]; o8[6] += pk * vf[6]; o8[7] += pk * vf[7];
      }
#pragma unroll
      for (int s = 0; s < 8; ++s){
        const int dl = (e << 3) + s;
        const float oc = depw[(h << 6) + dl] * fvv[dl >> 2] + depb[(h << 6) + dl];
        out[(((size_t)((b << 8) + (h << 6) + dl)) << 13) + w] = r1 * o8[s] + r2 * oc;
      }
    }
  }
}

// ---------------------------------------------------------------------------
// launch
// ---------------------------------------------------------------------------
extern "C" void kernel_launch(void* const* d_in, const int* in_sizes, int n_in,
                              void* d_out, int out_size, void* d_ws, size_t ws_size,
                              hipStream_t stream){
  (void)in_sizes; (void)n_in; (void)out_size; (void)ws_size;
  const float* x    = (const float*)d_in[0];
  const float* w1   = (const float*)d_in[1];
  const float* b1   = (const float*)d_in[2];
  const float* w2   = (const float*)d_in[3];
  const float* b2   = (const float*)d_in[4];
  const float* w3   = (const float*)d_in[5];
  const float* b3   = (const float*)d_in[6];
  const float* wp   = (const float*)d_in[7];
  // d_in[8] = bp : cancels analytically (pe - unfolded pe), unused
  const float* fcw  = (const float*)d_in[9];
  const float* depw = (const float*)d_in[10];
  const float* depb = (const float*)d_in[11];
  const float* r1p  = (const float*)d_in[12];
  const float* r2p  = (const float*)d_in[13];
  float* out = (float*)d_out;

  char* ws = (char*)d_ws;
  u16*   Wall = (u16*)(ws);                 // 896*256*2 = 458,752 B
  float* ball = (float*)(ws + 458752);      // 896*4     =   3,584 B

  k_build<<<dim3(896, 1, 1), 256, 0, stream>>>(w1, b1, w2, b2, w3, b3, fcw, Wall, ball);
  fused_acmix<<<dim3(512, 1, 1), 512, 0, stream>>>(Wall, ball, x, wp, depw, depb, r1p, r2p, out);
}

// Round 22
// 201.522 us; speedup vs baseline: 1.2702x; 1.0177x over previous
//
#include <hip/hip_runtime.h>
#include <stdint.h>
#include <stddef.h>

typedef unsigned short u16;
typedef unsigned int   u32;

typedef __attribute__((ext_vector_type(8))) short bf16x8;
typedef __attribute__((ext_vector_type(4))) float f32x4;

__device__ __forceinline__ float b2f_lo(u32 v) { return __uint_as_float(v << 16); }
__device__ __forceinline__ float b2f_hi(u32 v) { return __uint_as_float(v & 0xFFFF0000u); }
__device__ __forceinline__ u16 f2b(float f){
  u32 x = __float_as_uint(f);
  return (u16)((x + 0x7FFFu + ((x >> 16) & 1u)) >> 16);
}
__device__ __forceinline__ int refl(int w){ return w < 0 ? -w : (w > 8191 ? 16382 - w : w); }
__device__ __forceinline__ void up8(const uint4 v, float* f){
  f[0] = b2f_lo(v.x); f[1] = b2f_hi(v.x); f[2] = b2f_lo(v.y); f[3] = b2f_hi(v.y);
  f[4] = b2f_lo(v.z); f[5] = b2f_hi(v.z); f[6] = b2f_lo(v.w); f[7] = b2f_hi(v.w);
}

// ---------------------------------------------------------------------------
// K0: build combined weight matrix Wall[896][256] (bf16) + fp32 bias ball[896].
// rows 0-255: w1/b1, 256-511: w2/b2, 512-767: w3/b3, 768-831: fc-folded, rest 0.
// ---------------------------------------------------------------------------
__global__ __launch_bounds__(256) void k_build(const float* __restrict__ w1, const float* __restrict__ b1,
                                               const float* __restrict__ w2, const float* __restrict__ b2,
                                               const float* __restrict__ w3, const float* __restrict__ b3,
                                               const float* __restrict__ fcw,
                                               u16* __restrict__ Wall, float* __restrict__ ball){
  const int r = blockIdx.x, c = threadIdx.x;
  float v = 0.f, bv = 0.f;
  if (r < 256){      v = w1[(r << 8) + c];          bv = b1[r]; }
  else if (r < 512){ v = w2[((r - 256) << 8) + c];  bv = b2[r - 256]; }
  else if (r < 768){ v = w3[((r - 512) << 8) + c];  bv = b3[r - 512]; }
  else if (r < 832){
    const int d = r - 768;
    float s = 0.f, sbias = 0.f;
#pragma unroll
    for (int h = 0; h < 4; ++h){
      const int ch = (h << 6) + d;
      const float f1 = fcw[h], f2 = fcw[4 + h], f3 = fcw[8 + h];
      s     += f1 * w1[(ch << 8) + c] + f2 * w2[(ch << 8) + c] + f3 * w3[(ch << 8) + c];
      sbias += f1 * b1[ch] + f2 * b2[ch] + f3 * b3[ch];
    }
    v = s; bv = sbias;
  }
  Wall[(r << 8) + c] = f2b(v);
  if (c == 0) ball[r] = bv;
}

// ---------------------------------------------------------------------------
// K1 (fused, 8-wave GEMM + 2-way-split attention on ALL 512 threads).
// R21 isolated R18's failure to the es-split attention; root cause found in
// code review: R18 loaded the WRONG f-chunk (cf used es>>1 == 0) and only 8B
// into fq[4], while PV indexed fq[0..7] (OOB local read).  Stale-preloaded
// d_out masked it until the harness re-poisoned (first check "passed").
// This round: same split done right -- thread (es=t&1, h, wl) handles
// e in {4es..4es+3}; att/qd partner-reduced via __shfl_xor(.,1); f-chunk
// cf = 2h+es loaded as full uint4 into fq[8], index (ee<<1)+(s>>2)
// (= (dl>>2)-8*es, verified vs reference's group mapping f_ch = oc>>2).
// GEMM byte-identical to R21 (proven: FETCH 21MB/WRITE 41MB/VGPR 88).
//
// LDS map (bytes):
//   Bl  [80 r][256 k] bf16, chunk ^= (r&31)        40960   (r <-> w0-4+r)
//   As  [128 m][64 k] bf16, chunk ^= (row&7)       16384   (aliased by f tile)
//   Ql  [64 wl][256 ch] bf16, chunk ^= (wl&31)     32768
//   KVl [70 rr][512 ch] bf16, chunk ^= (rr&31)     71680   (rr <-> w0-3+rr)
//   wpL 64 f32                                       256
//   total 162048 B -> 1 block/CU, 8 waves = 2 waves/SIMD.
// grid 512 x 512 threads.
// ---------------------------------------------------------------------------
__global__ __launch_bounds__(512, 1) void fused_acmix(
    const u16* __restrict__ Wall, const float* __restrict__ ball,
    const float* __restrict__ x, const float* __restrict__ wp,
    const float* __restrict__ depw, const float* __restrict__ depb,
    const float* __restrict__ r1p, const float* __restrict__ r2p,
    float* __restrict__ out)
{
  __shared__ __align__(16) u16 Bl [80 * 256];
  __shared__ __align__(16) u16 As [128 * 64];
  __shared__ __align__(16) u16 Ql [64 * 256];
  __shared__ __align__(16) u16 KVl[70 * 512];
  __shared__ float wpL[64];
  u16* Fl = As;   // f tile aliases As after the last GEMM (guarded by barrier)

  const int bid = blockIdx.x;
  const int w_id = ((bid & 7) << 6) + (bid >> 3);   // XCD-contiguous stripes
  const int b = w_id >> 7;                           // 0..3
  const int w0 = (w_id & 127) << 6;

  const int t = threadIdx.x;
  const int wv = t >> 6, lane = t & 63;
  const int quad = lane >> 4, l15 = lane & 15;

  if (t < 64) wpL[t] = wp[t];

  // ---- stage Bl: task idx = cc*80 + r (lanes walk consecutive r => coalesced w) ----
  {
    const float* xb = x + ((size_t)b << 21);         // b*256*8192
    for (int idx = t; idx < 2560; idx += 512){
      const int cc = idx / 80;                       // 0..31 (8-channel chunk)
      const int r  = idx - cc * 80;                  // 0..79
      const int w  = refl(w0 - 4 + r);
      const float* px = xb + (((size_t)cc) << 16) + w;   // + cc*8*8192
      u32 pk[4];
#pragma unroll
      for (int jj = 0; jj < 4; ++jj){
        const float f0 = px[(size_t)(2 * jj)     << 13];
        const float f1 = px[(size_t)(2 * jj + 1) << 13];
        pk[jj] = (u32)f2b(f0) | ((u32)f2b(f1) << 16);
      }
      *(uint4*)((char*)Bl + r * 512 + ((cc ^ (r & 31)) << 4)) = make_uint4(pk[0], pk[1], pk[2], pk[3]);
    }
  }

  // ---- GEMM phase: 7 mt tiles (q q k k v v f), K=256 in 4 chunks of 64.
  //      8 waves; wave wv owns the 16-row strip mloc = wv*16..wv*16+15. ----
  uint4 ra[2];
  auto loadA = [&](int mt_, int kc_){
#pragma unroll
    for (int k4 = 0; k4 < 2; ++k4){
      const int task = t + (k4 << 9);               // 0..1023
      const int row = task >> 3, u = task & 7;
      ra[k4] = *(const uint4*)(Wall + (((mt_ << 7) + row) << 8) + (kc_ << 6) + (u << 3));
    }
  };
  loadA(0, 0);

#pragma unroll
  for (int mt = 0; mt < 7; ++mt){
    f32x4 acc[5] = {};
#pragma unroll
    for (int kc = 0; kc < 4; ++kc){
      __syncthreads();                              // As safe to overwrite (also fences Bl on iter 0)
#pragma unroll
      for (int k4 = 0; k4 < 2; ++k4){
        const int task = t + (k4 << 9);
        const int row = task >> 3, u = (task & 7) ^ (row & 7);
        *(uint4*)((char*)As + row * 128 + (u << 4)) = ra[k4];
      }
      __syncthreads();
      {
        const int idx = (mt << 2) + kc;
        if (idx < 27) loadA((idx + 1) >> 2, (idx + 1) & 3);  // prefetch next A-tile under MFMA
      }
#pragma unroll
      for (int ks = 0; ks < 2; ++ks){
        const int rowA = (wv << 4) + l15;
        const int ca = ((ks << 2) + quad) ^ (rowA & 7);
        const bf16x8 av = *(const bf16x8*)((const char*)As + rowA * 128 + (ca << 4));
#pragma unroll
        for (int j = 0; j < 5; ++j){
          const int rowB = (j << 4) + l15;
          const int cb = ((kc << 3) + (ks << 2) + quad) ^ (rowB & 31);
          const bf16x8 bv = *(const bf16x8*)((const char*)Bl + rowB * 512 + (cb << 4));
          acc[j] = __builtin_amdgcn_mfma_f32_16x16x32_bf16(av, bv, acc[j], 0, 0, 0);
        }
      }
    }

    // epilogue: C[m = wv*16+quad*4+reg][r = j*16+l15] -> route to LDS
    if (mt == 6) __syncthreads();                   // all As reads done before f-alias writes
    const int mloc = (wv << 4) + (quad << 2);       // 0..124 within mt
    const float4 bias = *(const float4*)(ball + (mt << 7) + mloc);
#pragma unroll
    for (int j = 0; j < 5; ++j){
      const int r = (j << 4) + l15;
      f32x4 c = acc[j];
      uint2 val;
      val.x = (u32)f2b(c.x + bias.x) | ((u32)f2b(c.y + bias.y) << 16);
      val.y = (u32)f2b(c.z + bias.z) | ((u32)f2b(c.w + bias.w) << 16);
      if (mt < 2){
        const int wl = r - 4;                       // q: center rows only
        if ((unsigned)wl < 64u){
          const int chunk = ((mt << 7) + mloc) >> 3;
          *(uint2*)((char*)Ql + wl * 512 + ((chunk ^ (wl & 31)) << 4) + ((quad & 1) << 3)) = val;
        }
      } else if (mt < 6){
        const int rr = r - 1;                       // k/v: 70 halo rows
        if ((unsigned)rr < 70u){
          const int chunk = (((mt - 2) << 7) + mloc) >> 3;   // k: 0..31, v: 32..63
          *(uint2*)((char*)KVl + rr * 1024 + ((chunk ^ (rr & 31)) << 4) + ((quad & 1) << 3)) = val;
        }
      } else {
        const int wl = r - 4;                       // f: center rows, first 64 m only
        if ((unsigned)wl < 64u && mloc < 64){
          const int chunk = mloc >> 3;              // 0..7
          *(uint2*)((char*)Fl + wl * 128 + ((chunk ^ (wl & 7)) << 4) + ((quad & 1) << 3)) = val;
        }
      }
    }
  }
  __syncthreads();

  // ---- attention: ALL 512 threads; thread = (es = t&1, h, wl);
  //      es handles e in {4es..4es+3} (q/k/v channels 32es..32es+31). ----
  const int es = t & 1;
  const int q_ = t >> 1;                 // 0..255
  const int h = q_ >> 6, wl = q_ & 63;
  const int w = w0 + wl;

  float att[7] = {0.f,0.f,0.f,0.f,0.f,0.f,0.f};
  float qd = 0.f;
#pragma unroll
  for (int ee = 0; ee < 4; ++ee){
    const int e = (es << 2) + ee;
    const int cq = (h << 3) + e;
    const uint4 q4 = *(const uint4*)((const char*)Ql + wl * 512 + ((cq ^ (wl & 31)) << 4));
    float qf[8]; up8(q4, qf);
#pragma unroll
    for (int d = 0; d < 8; ++d) qd += qf[d] * wpL[(e << 3) + d];
#pragma unroll
    for (int kk = 0; kk < 7; ++kk){
      const int rr = wl + kk;
      const uint4 k4 = *(const uint4*)((const char*)KVl + rr * 1024 + ((cq ^ (rr & 31)) << 4));
      float kf[8]; up8(k4, kf);
      att[kk] += qf[0]*kf[0] + qf[1]*kf[1] + qf[2]*kf[2] + qf[3]*kf[3]
               + qf[4]*kf[4] + qf[5]*kf[5] + qf[6]*kf[6] + qf[7]*kf[7];
    }
  }
  // partner reduce: lanes t and t^1 (same wave, same (h,wl), opposite es)
#pragma unroll
  for (int kk = 0; kk < 7; ++kk) att[kk] += __shfl_xor(att[kk], 1);
  qd += __shfl_xor(qd, 1);

  // positional term + scale + softmax (redundant x2, cheap)
  const float locw = -1.f + (2.f / 8191.f) * (float)w;
  float mx = -1e30f;
#pragma unroll
  for (int kk = 0; kk < 7; ++kk){
    const int wr = refl(w + kk - 3);
    const float lr = -1.f + (2.f / 8191.f) * (float)wr;
    att[kk] = 0.125f * (att[kk] + (locw - lr) * qd);
    mx = fmaxf(mx, att[kk]);
  }
  float p[7]; float ssum = 0.f;
#pragma unroll
  for (int kk = 0; kk < 7; ++kk){ p[kk] = __expf(att[kk] - mx); ssum += p[kk]; }
  const float inv = 1.f / ssum;
#pragma unroll
  for (int kk = 0; kk < 7; ++kk) p[kk] *= inv;

  // f values: this thread's dl range is [32es, 32es+32) -> f channels
  // h*16 + 8es .. +7 = chunk cf = 2h + es, FULL 16B -> fq[8].
  float fq[8];
  {
    const int cf = (h << 1) + es;
    const uint4 f4 = *(const uint4*)((const char*)Fl + wl * 128 + ((cf ^ (wl & 7)) << 4));
    up8(f4, fq);
  }
  const float r1 = r1p[0];
  const float r2 = r2p[0];

  // PV + dep-conv + combine + store (32 channels per thread: dl = 32es..32es+31)
#pragma unroll
  for (int ee = 0; ee < 4; ++ee){
    const int e = (es << 2) + ee;
    float o8[8] = {0.f,0.f,0.f,0.f,0.f,0.f,0.f,0.f};
#pragma unroll
    for (int kk = 0; kk < 7; ++kk){
      const int rr = wl + kk;
      const uint4 v4 = *(const uint4*)((const char*)KVl + rr * 1024 + (((32 + (h << 3) + e) ^ (rr & 31)) << 4));
      float vf[8]; up8(v4, vf);
      const float pk = p[kk];
      o8[0] += pk * vf[0]; o8[1] += pk * vf[1]; o8[2] += pk * vf[2]; o8[3] += pk * vf[3];
      o8[4] += pk * vf[4]; o8[5] += pk * vf[5]; o8[6] += pk * vf[6]; o8[7] += pk * vf[7];
    }
#pragma unroll
    for (int s = 0; s < 8; ++s){
      const int dl = (e << 3) + s;                  // 32es + 8ee + s
      // local f index = (dl>>2) - 8es = (ee<<1) + (s>>2), in [0,8)
      const float oc = depw[(h << 6) + dl] * fq[(ee << 1) + (s >> 2)] + depb[(h << 6) + dl];
      out[(((size_t)((b << 8) + (h << 6) + dl)) << 13) + w] = r1 * o8[s] + r2 * oc;
    }
  }
}

// ---------------------------------------------------------------------------
// launch
// ---------------------------------------------------------------------------
extern "C" void kernel_launch(void* const* d_in, const int* in_sizes, int n_in,
                              void* d_out, int out_size, void* d_ws, size_t ws_size,
                              hipStream_t stream){
  (void)in_sizes; (void)n_in; (void)out_size; (void)ws_size;
  const float* x    = (const float*)d_in[0];
  const float* w1   = (const float*)d_in[1];
  const float* b1   = (const float*)d_in[2];
  const float* w2   = (const float*)d_in[3];
  const float* b2   = (const float*)d_in[4];
  const float* w3   = (const float*)d_in[5];
  const float* b3   = (const float*)d_in[6];
  const float* wp   = (const float*)d_in[7];
  // d_in[8] = bp : cancels analytically (pe - unfolded pe), unused
  const float* fcw  = (const float*)d_in[9];
  const float* depw = (const float*)d_in[10];
  const float* depb = (const float*)d_in[11];
  const float* r1p  = (const float*)d_in[12];
  const float* r2p  = (const float*)d_in[13];
  float* out = (float*)d_out;

  char* ws = (char*)d_ws;
  u16*   Wall = (u16*)(ws);                 // 896*256*2 = 458,752 B
  float* ball = (float*)(ws + 458752);      // 896*4     =   3,584 B

  k_build<<<dim3(896, 1, 1), 256, 0, stream>>>(w1, b1, w2, b2, w3, b3, fcw, Wall, ball);
  fused_acmix<<<dim3(512, 1, 1), 512, 0, stream>>>(Wall, ball, x, wp, depw, depb, r1p, r2p, out);
}